// Round 3
// baseline (30557.269 us; speedup 1.0000x reference)
//
#include <hip/hip_runtime.h>
#include <hip/hip_cooperative_groups.h>
#include <math.h>

namespace cg = cooperative_groups;

#define S 2048
#define MARGIN 0.7f
#define ITERS 500

// ---------------------------------------------------------------------------
// init: log-marginals, zero accumulators
// ---------------------------------------------------------------------------
__global__ __launch_bounds__(256) void init_marg_k(const float* __restrict__ qa,
                                                   const float* __restrict__ ta,
                                                   float* __restrict__ lmu,
                                                   float* __restrict__ lnu,
                                                   float* __restrict__ vt,
                                                   float* __restrict__ dist2) {
  int i = blockIdx.x * 256 + threadIdx.x;
  lmu[i] = __logf(qa[i]);
  lnu[i] = __logf(ta[i]);
  vt[i] = 0.f;     // will accumulate y2 (vt init = v0 + y2 = y2 since v0 = 0)
  dist2[i] = 0.f;
}

// vt[j] += sum_d TF[d,j]^2   (8 j-blocks x 8 d-chunks, atomic combine)
__global__ __launch_bounds__(256) void colsumsq_k(const float* __restrict__ TF,
                                                  float* __restrict__ vt) {
  int jb = blockIdx.x & 7, dc = blockIdx.x >> 3;
  int j = jb * 256 + threadIdx.x;
  int d0 = dc * 256;
  float acc = 0.f;
  for (int d = d0; d < d0 + 256; ++d) {
    float v = TF[d * S + j];
    acc = fmaf(v, v, acc);
  }
  atomicAdd(&vt[j], acc);
}

// ---------------------------------------------------------------------------
// C[i,j] = alpha * sum_k A[k*S+i] * B[k*S+j]   (128x128 tile, BK=16, 8x8/thread)
// ---------------------------------------------------------------------------
__global__ __launch_bounds__(256) void gemm_tn_k(const float* __restrict__ A,
                                                 const float* __restrict__ B,
                                                 float* __restrict__ C, float alpha) {
  __shared__ float As[16][128];
  __shared__ float Bs[16][128];
  int t = threadIdx.x;
  int i0 = blockIdx.y * 128, j0 = blockIdx.x * 128;
  int tx = t & 15, ty = t >> 4;
  float acc[8][8];
#pragma unroll
  for (int r = 0; r < 8; ++r)
#pragma unroll
    for (int c = 0; c < 8; ++c) acc[r][c] = 0.f;

  int e = t * 4;
  int dd0 = e >> 7, ii = e & 127;
  int dd1 = dd0 + 8;
  for (int k0 = 0; k0 < S; k0 += 16) {
    float4 a0 = *(const float4*)&A[(k0 + dd0) * S + i0 + ii];
    float4 b0 = *(const float4*)&B[(k0 + dd0) * S + j0 + ii];
    float4 a1 = *(const float4*)&A[(k0 + dd1) * S + i0 + ii];
    float4 b1 = *(const float4*)&B[(k0 + dd1) * S + j0 + ii];
    __syncthreads();
    *(float4*)&As[dd0][ii] = a0; *(float4*)&Bs[dd0][ii] = b0;
    *(float4*)&As[dd1][ii] = a1; *(float4*)&Bs[dd1][ii] = b1;
    __syncthreads();
#pragma unroll
    for (int kk = 0; kk < 16; ++kk) {
      float a[8], b[8];
      *(float4*)&a[0] = *(const float4*)&As[kk][ty * 8];
      *(float4*)&a[4] = *(const float4*)&As[kk][ty * 8 + 4];
      *(float4*)&b[0] = *(const float4*)&Bs[kk][tx * 4];
      *(float4*)&b[4] = *(const float4*)&Bs[kk][64 + tx * 4];
#pragma unroll
      for (int r = 0; r < 8; ++r)
#pragma unroll
        for (int c = 0; c < 8; ++c) acc[r][c] = fmaf(a[r], b[c], acc[r][c]);
    }
  }
#pragma unroll
  for (int r = 0; r < 8; ++r) {
    int i = i0 + ty * 8 + r;
    float4 o0 = make_float4(acc[r][0] * alpha, acc[r][1] * alpha, acc[r][2] * alpha, acc[r][3] * alpha);
    float4 o1 = make_float4(acc[r][4] * alpha, acc[r][5] * alpha, acc[r][6] * alpha, acc[r][7] * alpha);
    *(float4*)&C[i * S + j0 + tx * 4] = o0;
    *(float4*)&C[i * S + j0 + 64 + tx * 4] = o1;
  }
}

// ---------------------------------------------------------------------------
// out[j*S+i] = in[i*S+j]  (64x64 LDS tiles)
// ---------------------------------------------------------------------------
__global__ __launch_bounds__(256) void transpose_k(const float* __restrict__ in,
                                                   float* __restrict__ out) {
  __shared__ float tile[64][65];
  int i0 = blockIdx.y * 64, j0 = blockIdx.x * 64;
  int tx = threadIdx.x & 63, ty = threadIdx.x >> 6;  // ty 0..3
#pragma unroll
  for (int r = 0; r < 16; ++r) {
    int row = r * 4 + ty;
    tile[row][tx] = in[(i0 + row) * S + j0 + tx];
  }
  __syncthreads();
#pragma unroll
  for (int r = 0; r < 16; ++r) {
    int row = r * 4 + ty;
    out[(j0 + row) * S + i0 + tx] = tile[tx][row];
  }
}

// ---------------------------------------------------------------------------
// PERSISTENT SINKHORN: one cooperative dispatch, all 500 iterations.
// Grid 256 blocks x 1024 threads (1 block/CU, co-resident). Each row owned by
// a wave pair (wave = 2*r_loc + h); each thread holds 16 cols of its Gp row
// and 16 cols of its GpT row in registers -> G is NEVER re-read (was 16.78 MB
// per phase from LLC). Per phase only the 8 KB potential vector is read per
// block. grid.sync() between phases replaces 1000 kernel dispatches.
// ---------------------------------------------------------------------------
__global__ __launch_bounds__(1024, 4) void sinkhorn_k(const float* __restrict__ Gp,
                                                      const float* __restrict__ GpT,
                                                      const float* __restrict__ lmu,
                                                      const float* __restrict__ lnu,
                                                      float* __restrict__ ut,
                                                      float* __restrict__ vt) {
  cg::grid_group grid = cg::this_grid();
  int t = threadIdx.x;
  int wave = t >> 6, lane = t & 63;
  int r_loc = wave >> 1;            // 0..7
  int h = wave & 1;                 // row half
  int row = blockIdx.x * 8 + r_loc;
  int cbase = h * 1024 + lane * 16;

  float a[16], b[16];
#pragma unroll
  for (int q = 0; q < 4; ++q) {
    *(float4*)&a[q * 4] = *(const float4*)&Gp[(size_t)row * S + cbase + q * 4];
    *(float4*)&b[q * 4] = *(const float4*)&GpT[(size_t)row * S + cbase + q * 4];
  }
  float lm = lmu[row];
  float ln = lnu[row];

  __shared__ float redmax[8][2];
  __shared__ float redsum[8][2];

  for (int it = 0; it < ITERS; ++it) {
    // ---- phase A: ut[row] = lmu[row] - LSE_c(Gp[row][c] + vt[c]) ----
    {
      float p[16];
#pragma unroll
      for (int q = 0; q < 4; ++q) *(float4*)&p[q * 4] = *(const float4*)&vt[cbase + q * 4];
      float m = -3.4e38f;
#pragma unroll
      for (int k = 0; k < 16; ++k) { p[k] += a[k]; m = fmaxf(m, p[k]); }
#pragma unroll
      for (int off = 32; off; off >>= 1) m = fmaxf(m, __shfl_xor(m, off));
      if (lane == 0) redmax[r_loc][h] = m;
      __syncthreads();
      m = fmaxf(redmax[r_loc][0], redmax[r_loc][1]);
      float s = 0.f;
#pragma unroll
      for (int k = 0; k < 16; ++k) s += __expf(p[k] - m);
#pragma unroll
      for (int off = 32; off; off >>= 1) s += __shfl_xor(s, off);
      if (lane == 0) redsum[r_loc][h] = s;
      __syncthreads();
      if (h == 0 && lane == 0)
        ut[row] = lm - (m + __logf(redsum[r_loc][0] + redsum[r_loc][1]));
    }
    grid.sync();
    // ---- phase B: vt[row] = lnu[row] - LSE_c(GpT[row][c] + ut[c]) ----
    {
      float p[16];
#pragma unroll
      for (int q = 0; q < 4; ++q) *(float4*)&p[q * 4] = *(const float4*)&ut[cbase + q * 4];
      float m = -3.4e38f;
#pragma unroll
      for (int k = 0; k < 16; ++k) { p[k] += b[k]; m = fmaxf(m, p[k]); }
#pragma unroll
      for (int off = 32; off; off >>= 1) m = fmaxf(m, __shfl_xor(m, off));
      if (lane == 0) redmax[r_loc][h] = m;
      __syncthreads();
      m = fmaxf(redmax[r_loc][0], redmax[r_loc][1]);
      float s = 0.f;
#pragma unroll
      for (int k = 0; k < 16; ++k) s += __expf(p[k] - m);
#pragma unroll
      for (int off = 32; off; off >>= 1) s += __shfl_xor(s, off);
      if (lane == 0) redsum[r_loc][h] = s;
      __syncthreads();
      if (h == 0 && lane == 0)
        vt[row] = ln - (m + __logf(redsum[r_loc][0] + redsum[r_loc][1]));
    }
    grid.sync();
  }
}

// ---------------------------------------------------------------------------
// RT[d,i] = sum_j TF[d,j] * exp( GpT[j*S+i] + ut[i] + vt[j] )
// (C = A * P^T with P^T generated on the fly into LDS; 128x128 tile, BK=16)
// ---------------------------------------------------------------------------
__global__ __launch_bounds__(256) void rt_gemm_k(const float* __restrict__ TF,
                                                 const float* __restrict__ GpT,
                                                 const float* __restrict__ ut,
                                                 const float* __restrict__ vt,
                                                 float* __restrict__ RT) {
  __shared__ float As[16][128];  // As[kk][dd] = TF[(d0+dd)*S + k0+kk]
  __shared__ float Bs[16][128];  // Bs[kk][ii] = P^T[k0+kk, i0+ii]
  int t = threadIdx.x;
  int d0 = blockIdx.y * 128, i0 = blockIdx.x * 128;
  int tx = t & 15, ty = t >> 4;
  float acc[8][8];
#pragma unroll
  for (int r = 0; r < 8; ++r)
#pragma unroll
    for (int c = 0; c < 8; ++c) acc[r][c] = 0.f;

  int akk = (t * 4) & 15, add0 = t >> 2;            // add0 in 0..63, + 64 for 2nd half
  int eb = t * 4;
  int bkk0 = eb >> 7, bii = eb & 127, bkk1 = bkk0 + 8;
  float4 u4 = *(const float4*)&ut[i0 + bii];        // loop-invariant

  for (int k0 = 0; k0 < S; k0 += 16) {
    float4 av0 = *(const float4*)&TF[(d0 + add0) * S + k0 + akk];
    float4 av1 = *(const float4*)&TF[(d0 + add0 + 64) * S + k0 + akk];
    float4 g0 = *(const float4*)&GpT[(k0 + bkk0) * S + i0 + bii];
    float4 g1 = *(const float4*)&GpT[(k0 + bkk1) * S + i0 + bii];
    float v0 = vt[k0 + bkk0], v1 = vt[k0 + bkk1];
    __syncthreads();
    As[akk + 0][add0] = av0.x; As[akk + 1][add0] = av0.y;
    As[akk + 2][add0] = av0.z; As[akk + 3][add0] = av0.w;
    As[akk + 0][add0 + 64] = av1.x; As[akk + 1][add0 + 64] = av1.y;
    As[akk + 2][add0 + 64] = av1.z; As[akk + 3][add0 + 64] = av1.w;
    float4 p0 = make_float4(__expf(g0.x + u4.x + v0), __expf(g0.y + u4.y + v0),
                            __expf(g0.z + u4.z + v0), __expf(g0.w + u4.w + v0));
    float4 p1 = make_float4(__expf(g1.x + u4.x + v1), __expf(g1.y + u4.y + v1),
                            __expf(g1.z + u4.z + v1), __expf(g1.w + u4.w + v1));
    *(float4*)&Bs[bkk0][bii] = p0;
    *(float4*)&Bs[bkk1][bii] = p1;
    __syncthreads();
#pragma unroll
    for (int kk = 0; kk < 16; ++kk) {
      float a[8], b[8];
      *(float4*)&a[0] = *(const float4*)&As[kk][ty * 8];
      *(float4*)&a[4] = *(const float4*)&As[kk][ty * 8 + 4];
      *(float4*)&b[0] = *(const float4*)&Bs[kk][tx * 4];
      *(float4*)&b[4] = *(const float4*)&Bs[kk][64 + tx * 4];
#pragma unroll
      for (int r = 0; r < 8; ++r)
#pragma unroll
        for (int c = 0; c < 8; ++c) acc[r][c] = fmaf(a[r], b[c], acc[r][c]);
    }
  }
#pragma unroll
  for (int r = 0; r < 8; ++r) {
    int d = d0 + ty * 8 + r;
    *(float4*)&RT[d * S + i0 + tx * 4] = *(float4*)&acc[r][0];
    *(float4*)&RT[d * S + i0 + 64 + tx * 4] = *(float4*)&acc[r][4];
  }
}

// dist2[i] += sum_{d in chunk} (qa[i]*QF[d,i] - RT[d,i])^2
__global__ __launch_bounds__(256) void dist2_partial_k(const float* __restrict__ QF,
                                                       const float* __restrict__ RT,
                                                       const float* __restrict__ qa,
                                                       float* __restrict__ dist2) {
  int ib = blockIdx.x & 7, dc = blockIdx.x >> 3;
  int i = ib * 256 + threadIdx.x;
  float qai = qa[i];
  float acc = 0.f;
  int d0 = dc * 256;
  for (int d = d0; d < d0 + 256; ++d) {
    float q = QF[d * S + i];
    float r = RT[d * S + i];
    float x = fmaf(qai, q, -r);
    acc = fmaf(x, x, acc);
  }
  atomicAdd(&dist2[i], acc);
}

__global__ __launch_bounds__(256) void loss_final_k(const float* __restrict__ dist2,
                                                    const float* __restrict__ label,
                                                    float* __restrict__ out) {
  int t = threadIdx.x;
  float acc = 0.f;
#pragma unroll
  for (int k = 0; k < 8; ++k) {
    int i = t + k * 256;
    float d2 = dist2[i];
    float dist = sqrtf(d2);
    float lab = label[i];
    float neg = fmaxf(MARGIN - dist, 0.f);
    acc += 0.5f * lab * d2 + 0.5f * (1.f - lab) * neg * neg;
  }
#pragma unroll
  for (int off = 32; off; off >>= 1) acc += __shfl_xor(acc, off);
  __shared__ float wsum[4];
  int wave = t >> 6, lane = t & 63;
  if (lane == 0) wsum[wave] = acc;
  __syncthreads();
  if (t == 0) out[0] = wsum[0] + wsum[1] + wsum[2] + wsum[3];
}

// ---------------------------------------------------------------------------
extern "C" void kernel_launch(void* const* d_in, const int* in_sizes, int n_in,
                              void* d_out, int out_size, void* d_ws, size_t ws_size,
                              hipStream_t stream) {
  const float* QF  = (const float*)d_in[0];  // [D, m] d-major
  const float* qa  = (const float*)d_in[1];  // [m]
  const float* TF  = (const float*)d_in[2];  // [D, n] d-major
  const float* ta  = (const float*)d_in[3];  // [n]
  const float* lab = (const float*)d_in[4];  // [m]
  float* out = (float*)d_out;

  float* ws = (float*)d_ws;
  float* Gp    = ws;                  // S*S : G' = -2 X^T Y  (reused as RT later)
  float* GpT   = Gp + S * S;          // S*S : G'^T
  float* ut    = GpT + S * S;         // S
  float* vt    = ut + S;              // S
  float* lmu   = vt + S;              // S
  float* lnu   = lmu + S;             // S
  float* dist2 = lnu + S;             // S
  // total: 2*S*S + 5*S floats ~= 33.6 MB

  init_marg_k<<<8, 256, 0, stream>>>(qa, ta, lmu, lnu, vt, dist2);
  colsumsq_k<<<64, 256, 0, stream>>>(TF, vt);  // vt = y2 (== v0 + y2)
  gemm_tn_k<<<dim3(16, 16), 256, 0, stream>>>(QF, TF, Gp, -2.0f);
  transpose_k<<<dim3(32, 32), 256, 0, stream>>>(Gp, GpT);

  {
    const float* Gp_c = Gp;
    const float* GpT_c = GpT;
    const float* lmu_c = lmu;
    const float* lnu_c = lnu;
    float* ut_p = ut;
    float* vt_p = vt;
    void* kargs[] = {(void*)&Gp_c, (void*)&GpT_c, (void*)&lmu_c,
                     (void*)&lnu_c, (void*)&ut_p, (void*)&vt_p};
    hipLaunchCooperativeKernel((void*)sinkhorn_k, dim3(256), dim3(1024),
                               kargs, 0, stream);
  }

  // RT = P @ tf computed transposed: RT[d,i]; aliases Gp (G' dead after sinkhorn)
  rt_gemm_k<<<dim3(16, 16), 256, 0, stream>>>(TF, GpT, ut, vt, Gp);
  dist2_partial_k<<<64, 256, 0, stream>>>(QF, Gp, qa, dist2);
  loss_final_k<<<1, 256, 0, stream>>>(dist2, lab, out);
}

// Round 4
// 16559.789 us; speedup vs baseline: 1.8453x; 1.8453x over previous
//
#include <hip/hip_runtime.h>
#include <math.h>

#define S 2048
#define MARGIN 0.7f
#define ITERS 500
#define NBLK 256

// ---------------------------------------------------------------------------
// init: log-marginals, zero accumulators + barrier counter
// ---------------------------------------------------------------------------
__global__ __launch_bounds__(256) void init_marg_k(const float* __restrict__ qa,
                                                   const float* __restrict__ ta,
                                                   float* __restrict__ lmu,
                                                   float* __restrict__ lnu,
                                                   float* __restrict__ vt,
                                                   float* __restrict__ dist2,
                                                   unsigned* __restrict__ bar) {
  int i = blockIdx.x * 256 + threadIdx.x;
  lmu[i] = __logf(qa[i]);
  lnu[i] = __logf(ta[i]);
  vt[i] = 0.f;     // will accumulate y2 (vt init = v0 + y2 = y2 since v0 = 0)
  dist2[i] = 0.f;
  if (blockIdx.x == 0 && threadIdx.x == 0) *bar = 0u;
}

// vt[j] += sum_d TF[d,j]^2   (8 j-blocks x 8 d-chunks, atomic combine)
__global__ __launch_bounds__(256) void colsumsq_k(const float* __restrict__ TF,
                                                  float* __restrict__ vt) {
  int jb = blockIdx.x & 7, dc = blockIdx.x >> 3;
  int j = jb * 256 + threadIdx.x;
  int d0 = dc * 256;
  float acc = 0.f;
  for (int d = d0; d < d0 + 256; ++d) {
    float v = TF[d * S + j];
    acc = fmaf(v, v, acc);
  }
  atomicAdd(&vt[j], acc);
}

// ---------------------------------------------------------------------------
// C[i,j] = alpha * sum_k A[k*S+i] * B[k*S+j]   (128x128 tile, BK=16, 8x8/thread)
// ---------------------------------------------------------------------------
__global__ __launch_bounds__(256) void gemm_tn_k(const float* __restrict__ A,
                                                 const float* __restrict__ B,
                                                 float* __restrict__ C, float alpha) {
  __shared__ float As[16][128];
  __shared__ float Bs[16][128];
  int t = threadIdx.x;
  int i0 = blockIdx.y * 128, j0 = blockIdx.x * 128;
  int tx = t & 15, ty = t >> 4;
  float acc[8][8];
#pragma unroll
  for (int r = 0; r < 8; ++r)
#pragma unroll
    for (int c = 0; c < 8; ++c) acc[r][c] = 0.f;

  int e = t * 4;
  int dd0 = e >> 7, ii = e & 127;
  int dd1 = dd0 + 8;
  for (int k0 = 0; k0 < S; k0 += 16) {
    float4 a0 = *(const float4*)&A[(k0 + dd0) * S + i0 + ii];
    float4 b0 = *(const float4*)&B[(k0 + dd0) * S + j0 + ii];
    float4 a1 = *(const float4*)&A[(k0 + dd1) * S + i0 + ii];
    float4 b1 = *(const float4*)&B[(k0 + dd1) * S + j0 + ii];
    __syncthreads();
    *(float4*)&As[dd0][ii] = a0; *(float4*)&Bs[dd0][ii] = b0;
    *(float4*)&As[dd1][ii] = a1; *(float4*)&Bs[dd1][ii] = b1;
    __syncthreads();
#pragma unroll
    for (int kk = 0; kk < 16; ++kk) {
      float a[8], b[8];
      *(float4*)&a[0] = *(const float4*)&As[kk][ty * 8];
      *(float4*)&a[4] = *(const float4*)&As[kk][ty * 8 + 4];
      *(float4*)&b[0] = *(const float4*)&Bs[kk][tx * 4];
      *(float4*)&b[4] = *(const float4*)&Bs[kk][64 + tx * 4];
#pragma unroll
      for (int r = 0; r < 8; ++r)
#pragma unroll
        for (int c = 0; c < 8; ++c) acc[r][c] = fmaf(a[r], b[c], acc[r][c]);
    }
  }
#pragma unroll
  for (int r = 0; r < 8; ++r) {
    int i = i0 + ty * 8 + r;
    float4 o0 = make_float4(acc[r][0] * alpha, acc[r][1] * alpha, acc[r][2] * alpha, acc[r][3] * alpha);
    float4 o1 = make_float4(acc[r][4] * alpha, acc[r][5] * alpha, acc[r][6] * alpha, acc[r][7] * alpha);
    *(float4*)&C[i * S + j0 + tx * 4] = o0;
    *(float4*)&C[i * S + j0 + 64 + tx * 4] = o1;
  }
}

// ---------------------------------------------------------------------------
// out[j*S+i] = in[i*S+j]  (64x64 LDS tiles)
// ---------------------------------------------------------------------------
__global__ __launch_bounds__(256) void transpose_k(const float* __restrict__ in,
                                                   float* __restrict__ out) {
  __shared__ float tile[64][65];
  int i0 = blockIdx.y * 64, j0 = blockIdx.x * 64;
  int tx = threadIdx.x & 63, ty = threadIdx.x >> 6;  // ty 0..3
#pragma unroll
  for (int r = 0; r < 16; ++r) {
    int row = r * 4 + ty;
    tile[row][tx] = in[(i0 + row) * S + j0 + tx];
  }
  __syncthreads();
#pragma unroll
  for (int r = 0; r < 16; ++r) {
    int row = r * 4 + ty;
    out[(j0 + row) * S + i0 + tx] = tile[tx][row];
  }
}

// ---------------------------------------------------------------------------
// Fast grid barrier: monotonic agent-scope counter. One atomicAdd per block,
// spin on counter >= 256*barnum. Replaces cg::grid.sync() which measured
// ~30 us/sync on gfx950 (round 3: sinkhorn 30 ms, VALUBusy 3%).
// Requires all blocks co-resident -> launched via hipLaunchCooperativeKernel.
// ---------------------------------------------------------------------------
__device__ __forceinline__ void fast_barrier(unsigned* __restrict__ bar, unsigned target) {
  __syncthreads();
  if (threadIdx.x == 0) {
    __hip_atomic_fetch_add(bar, 1u, __ATOMIC_ACQ_REL, __HIP_MEMORY_SCOPE_AGENT);
    while (__hip_atomic_load(bar, __ATOMIC_ACQUIRE, __HIP_MEMORY_SCOPE_AGENT) < target) {
      __builtin_amdgcn_s_sleep(1);
    }
  }
  __syncthreads();
}

// ---------------------------------------------------------------------------
// PERSISTENT SINKHORN: one cooperative dispatch, all 500 iterations.
// Grid 256 blocks x 1024 threads (1 block/CU, co-resident). Each row owned by
// a wave pair (wave = 2*r_loc + h); each thread holds 16 cols of its Gp row
// and 16 cols of its GpT row in registers -> G is NEVER re-read during
// iteration (FETCH_SIZE ~112 MB/dispatch = initial load only, round-3 data).
// ---------------------------------------------------------------------------
__global__ __launch_bounds__(1024, 4) void sinkhorn_k(const float* __restrict__ Gp,
                                                      const float* __restrict__ GpT,
                                                      const float* __restrict__ lmu,
                                                      const float* __restrict__ lnu,
                                                      float* __restrict__ ut,
                                                      float* __restrict__ vt,
                                                      unsigned* __restrict__ bar) {
  int t = threadIdx.x;
  int wave = t >> 6, lane = t & 63;
  int r_loc = wave >> 1;            // 0..7
  int h = wave & 1;                 // row half
  int row = blockIdx.x * 8 + r_loc;
  int cbase = h * 1024 + lane * 16;

  float a[16], b[16];
#pragma unroll
  for (int q = 0; q < 4; ++q) {
    *(float4*)&a[q * 4] = *(const float4*)&Gp[(size_t)row * S + cbase + q * 4];
    *(float4*)&b[q * 4] = *(const float4*)&GpT[(size_t)row * S + cbase + q * 4];
  }
  float lm = lmu[row];
  float ln = lnu[row];

  __shared__ float redmax[8][2];
  __shared__ float redsum[8][2];

  unsigned barnum = 0;
  for (int it = 0; it < ITERS; ++it) {
    // ---- phase A: ut[row] = lmu[row] - LSE_c(Gp[row][c] + vt[c]) ----
    {
      float p[16];
#pragma unroll
      for (int q = 0; q < 4; ++q) *(float4*)&p[q * 4] = *(const float4*)&vt[cbase + q * 4];
      float m = -3.4e38f;
#pragma unroll
      for (int k = 0; k < 16; ++k) { p[k] += a[k]; m = fmaxf(m, p[k]); }
#pragma unroll
      for (int off = 32; off; off >>= 1) m = fmaxf(m, __shfl_xor(m, off));
      if (lane == 0) redmax[r_loc][h] = m;
      __syncthreads();
      m = fmaxf(redmax[r_loc][0], redmax[r_loc][1]);
      float s = 0.f;
#pragma unroll
      for (int k = 0; k < 16; ++k) s += __expf(p[k] - m);
#pragma unroll
      for (int off = 32; off; off >>= 1) s += __shfl_xor(s, off);
      if (lane == 0) redsum[r_loc][h] = s;
      __syncthreads();
      if (h == 0 && lane == 0)
        ut[row] = lm - (m + __logf(redsum[r_loc][0] + redsum[r_loc][1]));
    }
    ++barnum;
    fast_barrier(bar, barnum * NBLK);
    // ---- phase B: vt[row] = lnu[row] - LSE_c(GpT[row][c] + ut[c]) ----
    {
      float p[16];
#pragma unroll
      for (int q = 0; q < 4; ++q) *(float4*)&p[q * 4] = *(const float4*)&ut[cbase + q * 4];
      float m = -3.4e38f;
#pragma unroll
      for (int k = 0; k < 16; ++k) { p[k] += b[k]; m = fmaxf(m, p[k]); }
#pragma unroll
      for (int off = 32; off; off >>= 1) m = fmaxf(m, __shfl_xor(m, off));
      if (lane == 0) redmax[r_loc][h] = m;
      __syncthreads();
      m = fmaxf(redmax[r_loc][0], redmax[r_loc][1]);
      float s = 0.f;
#pragma unroll
      for (int k = 0; k < 16; ++k) s += __expf(p[k] - m);
#pragma unroll
      for (int off = 32; off; off >>= 1) s += __shfl_xor(s, off);
      if (lane == 0) redsum[r_loc][h] = s;
      __syncthreads();
      if (h == 0 && lane == 0)
        vt[row] = ln - (m + __logf(redsum[r_loc][0] + redsum[r_loc][1]));
    }
    if (it + 1 < ITERS) {           // final visibility handled by dispatch boundary
      ++barnum;
      fast_barrier(bar, barnum * NBLK);
    }
  }
}

// ---------------------------------------------------------------------------
// RT[d,i] = sum_j TF[d,j] * exp( GpT[j*S+i] + ut[i] + vt[j] )
// (C = A * P^T with P^T generated on the fly into LDS; 128x128 tile, BK=16)
// ---------------------------------------------------------------------------
__global__ __launch_bounds__(256) void rt_gemm_k(const float* __restrict__ TF,
                                                 const float* __restrict__ GpT,
                                                 const float* __restrict__ ut,
                                                 const float* __restrict__ vt,
                                                 float* __restrict__ RT) {
  __shared__ float As[16][128];  // As[kk][dd] = TF[(d0+dd)*S + k0+kk]
  __shared__ float Bs[16][128];  // Bs[kk][ii] = P^T[k0+kk, i0+ii]
  int t = threadIdx.x;
  int d0 = blockIdx.y * 128, i0 = blockIdx.x * 128;
  int tx = t & 15, ty = t >> 4;
  float acc[8][8];
#pragma unroll
  for (int r = 0; r < 8; ++r)
#pragma unroll
    for (int c = 0; c < 8; ++c) acc[r][c] = 0.f;

  int akk = (t * 4) & 15, add0 = t >> 2;            // add0 in 0..63, + 64 for 2nd half
  int eb = t * 4;
  int bkk0 = eb >> 7, bii = eb & 127, bkk1 = bkk0 + 8;
  float4 u4 = *(const float4*)&ut[i0 + bii];        // loop-invariant

  for (int k0 = 0; k0 < S; k0 += 16) {
    float4 av0 = *(const float4*)&TF[(d0 + add0) * S + k0 + akk];
    float4 av1 = *(const float4*)&TF[(d0 + add0 + 64) * S + k0 + akk];
    float4 g0 = *(const float4*)&GpT[(k0 + bkk0) * S + i0 + bii];
    float4 g1 = *(const float4*)&GpT[(k0 + bkk1) * S + i0 + bii];
    float v0 = vt[k0 + bkk0], v1 = vt[k0 + bkk1];
    __syncthreads();
    As[akk + 0][add0] = av0.x; As[akk + 1][add0] = av0.y;
    As[akk + 2][add0] = av0.z; As[akk + 3][add0] = av0.w;
    As[akk + 0][add0 + 64] = av1.x; As[akk + 1][add0 + 64] = av1.y;
    As[akk + 2][add0 + 64] = av1.z; As[akk + 3][add0 + 64] = av1.w;
    float4 p0 = make_float4(__expf(g0.x + u4.x + v0), __expf(g0.y + u4.y + v0),
                            __expf(g0.z + u4.z + v0), __expf(g0.w + u4.w + v0));
    float4 p1 = make_float4(__expf(g1.x + u4.x + v1), __expf(g1.y + u4.y + v1),
                            __expf(g1.z + u4.z + v1), __expf(g1.w + u4.w + v1));
    *(float4*)&Bs[bkk0][bii] = p0;
    *(float4*)&Bs[bkk1][bii] = p1;
    __syncthreads();
#pragma unroll
    for (int kk = 0; kk < 16; ++kk) {
      float a[8], b[8];
      *(float4*)&a[0] = *(const float4*)&As[kk][ty * 8];
      *(float4*)&a[4] = *(const float4*)&As[kk][ty * 8 + 4];
      *(float4*)&b[0] = *(const float4*)&Bs[kk][tx * 4];
      *(float4*)&b[4] = *(const float4*)&Bs[kk][64 + tx * 4];
#pragma unroll
      for (int r = 0; r < 8; ++r)
#pragma unroll
        for (int c = 0; c < 8; ++c) acc[r][c] = fmaf(a[r], b[c], acc[r][c]);
    }
  }
#pragma unroll
  for (int r = 0; r < 8; ++r) {
    int d = d0 + ty * 8 + r;
    *(float4*)&RT[d * S + i0 + tx * 4] = *(float4*)&acc[r][0];
    *(float4*)&RT[d * S + i0 + 64 + tx * 4] = *(float4*)&acc[r][4];
  }
}

// dist2[i] += sum_{d in chunk} (qa[i]*QF[d,i] - RT[d,i])^2
__global__ __launch_bounds__(256) void dist2_partial_k(const float* __restrict__ QF,
                                                       const float* __restrict__ RT,
                                                       const float* __restrict__ qa,
                                                       float* __restrict__ dist2) {
  int ib = blockIdx.x & 7, dc = blockIdx.x >> 3;
  int i = ib * 256 + threadIdx.x;
  float qai = qa[i];
  float acc = 0.f;
  int d0 = dc * 256;
  for (int d = d0; d < d0 + 256; ++d) {
    float q = QF[d * S + i];
    float r = RT[d * S + i];
    float x = fmaf(qai, q, -r);
    acc = fmaf(x, x, acc);
  }
  atomicAdd(&dist2[i], acc);
}

__global__ __launch_bounds__(256) void loss_final_k(const float* __restrict__ dist2,
                                                    const float* __restrict__ label,
                                                    float* __restrict__ out) {
  int t = threadIdx.x;
  float acc = 0.f;
#pragma unroll
  for (int k = 0; k < 8; ++k) {
    int i = t + k * 256;
    float d2 = dist2[i];
    float dist = sqrtf(d2);
    float lab = label[i];
    float neg = fmaxf(MARGIN - dist, 0.f);
    acc += 0.5f * lab * d2 + 0.5f * (1.f - lab) * neg * neg;
  }
#pragma unroll
  for (int off = 32; off; off >>= 1) acc += __shfl_xor(acc, off);
  __shared__ float wsum[4];
  int wave = t >> 6, lane = t & 63;
  if (lane == 0) wsum[wave] = acc;
  __syncthreads();
  if (t == 0) out[0] = wsum[0] + wsum[1] + wsum[2] + wsum[3];
}

// ---------------------------------------------------------------------------
extern "C" void kernel_launch(void* const* d_in, const int* in_sizes, int n_in,
                              void* d_out, int out_size, void* d_ws, size_t ws_size,
                              hipStream_t stream) {
  const float* QF  = (const float*)d_in[0];  // [D, m] d-major
  const float* qa  = (const float*)d_in[1];  // [m]
  const float* TF  = (const float*)d_in[2];  // [D, n] d-major
  const float* ta  = (const float*)d_in[3];  // [n]
  const float* lab = (const float*)d_in[4];  // [m]
  float* out = (float*)d_out;

  float* ws = (float*)d_ws;
  float* Gp    = ws;                  // S*S : G' = -2 X^T Y  (reused as RT later)
  float* GpT   = Gp + S * S;          // S*S : G'^T
  float* ut    = GpT + S * S;         // S
  float* vt    = ut + S;              // S
  float* lmu   = vt + S;              // S
  float* lnu   = lmu + S;             // S
  float* dist2 = lnu + S;             // S
  unsigned* bar = (unsigned*)(dist2 + S);
  // total: 2*S*S + 5*S floats + 1 uint ~= 33.6 MB

  init_marg_k<<<8, 256, 0, stream>>>(qa, ta, lmu, lnu, vt, dist2, bar);
  colsumsq_k<<<64, 256, 0, stream>>>(TF, vt);  // vt = y2 (== v0 + y2)
  gemm_tn_k<<<dim3(16, 16), 256, 0, stream>>>(QF, TF, Gp, -2.0f);
  transpose_k<<<dim3(32, 32), 256, 0, stream>>>(Gp, GpT);

  {
    const float* Gp_c = Gp;
    const float* GpT_c = GpT;
    const float* lmu_c = lmu;
    const float* lnu_c = lnu;
    float* ut_p = ut;
    float* vt_p = vt;
    unsigned* bar_p = bar;
    void* kargs[] = {(void*)&Gp_c, (void*)&GpT_c, (void*)&lmu_c,
                     (void*)&lnu_c, (void*)&ut_p, (void*)&vt_p, (void*)&bar_p};
    hipLaunchCooperativeKernel((void*)sinkhorn_k, dim3(NBLK), dim3(1024),
                               kargs, 0, stream);
  }

  // RT = P @ tf computed transposed: RT[d,i]; aliases Gp (G' dead after sinkhorn)
  rt_gemm_k<<<dim3(16, 16), 256, 0, stream>>>(TF, GpT, ut, vt, Gp);
  dist2_partial_k<<<64, 256, 0, stream>>>(QF, Gp, qa, dist2);
  loss_final_k<<<1, 256, 0, stream>>>(dist2, lab, out);
}

// Round 5
// 10672.470 us; speedup vs baseline: 2.8632x; 1.5516x over previous
//
#include <hip/hip_runtime.h>
#include <math.h>

#define S 2048
#define MARGIN 0.7f
#define ITERS 500
#define NBLK 256
#define FLAG_STRIDE 32   // 32 uints = 128 B = one cache line per block flag

// ---------------------------------------------------------------------------
// init: log-marginals, zero accumulators + barrier flags
// ---------------------------------------------------------------------------
__global__ __launch_bounds__(256) void init_marg_k(const float* __restrict__ qa,
                                                   const float* __restrict__ ta,
                                                   float* __restrict__ lmu,
                                                   float* __restrict__ lnu,
                                                   float* __restrict__ vt,
                                                   float* __restrict__ dist2,
                                                   unsigned* __restrict__ arrive,
                                                   unsigned* __restrict__ go) {
  int i = blockIdx.x * 256 + threadIdx.x;
  lmu[i] = __logf(qa[i]);
  lnu[i] = __logf(ta[i]);
  vt[i] = 0.f;     // will accumulate y2 (vt init = v0 + y2 = y2 since v0 = 0)
  dist2[i] = 0.f;
  // zero all NBLK*FLAG_STRIDE arrival words (2048 threads x 4 each = 8192)
#pragma unroll
  for (int k = 0; k < 4; ++k) arrive[i * 4 + k] = 0u;
  if (i == 0) *go = 0u;
}

// vt[j] += sum_d TF[d,j]^2   (8 j-blocks x 8 d-chunks, atomic combine)
__global__ __launch_bounds__(256) void colsumsq_k(const float* __restrict__ TF,
                                                  float* __restrict__ vt) {
  int jb = blockIdx.x & 7, dc = blockIdx.x >> 3;
  int j = jb * 256 + threadIdx.x;
  int d0 = dc * 256;
  float acc = 0.f;
  for (int d = d0; d < d0 + 256; ++d) {
    float v = TF[d * S + j];
    acc = fmaf(v, v, acc);
  }
  atomicAdd(&vt[j], acc);
}

// ---------------------------------------------------------------------------
// C[i,j] = alpha * sum_k A[k*S+i] * B[k*S+j]   (128x128 tile, BK=16, 8x8/thread)
// ---------------------------------------------------------------------------
__global__ __launch_bounds__(256) void gemm_tn_k(const float* __restrict__ A,
                                                 const float* __restrict__ B,
                                                 float* __restrict__ C, float alpha) {
  __shared__ float As[16][128];
  __shared__ float Bs[16][128];
  int t = threadIdx.x;
  int i0 = blockIdx.y * 128, j0 = blockIdx.x * 128;
  int tx = t & 15, ty = t >> 4;
  float acc[8][8];
#pragma unroll
  for (int r = 0; r < 8; ++r)
#pragma unroll
    for (int c = 0; c < 8; ++c) acc[r][c] = 0.f;

  int e = t * 4;
  int dd0 = e >> 7, ii = e & 127;
  int dd1 = dd0 + 8;
  for (int k0 = 0; k0 < S; k0 += 16) {
    float4 a0 = *(const float4*)&A[(k0 + dd0) * S + i0 + ii];
    float4 b0 = *(const float4*)&B[(k0 + dd0) * S + j0 + ii];
    float4 a1 = *(const float4*)&A[(k0 + dd1) * S + i0 + ii];
    float4 b1 = *(const float4*)&B[(k0 + dd1) * S + j0 + ii];
    __syncthreads();
    *(float4*)&As[dd0][ii] = a0; *(float4*)&Bs[dd0][ii] = b0;
    *(float4*)&As[dd1][ii] = a1; *(float4*)&Bs[dd1][ii] = b1;
    __syncthreads();
#pragma unroll
    for (int kk = 0; kk < 16; ++kk) {
      float a[8], b[8];
      *(float4*)&a[0] = *(const float4*)&As[kk][ty * 8];
      *(float4*)&a[4] = *(const float4*)&As[kk][ty * 8 + 4];
      *(float4*)&b[0] = *(const float4*)&Bs[kk][tx * 4];
      *(float4*)&b[4] = *(const float4*)&Bs[kk][64 + tx * 4];
#pragma unroll
      for (int r = 0; r < 8; ++r)
#pragma unroll
        for (int c = 0; c < 8; ++c) acc[r][c] = fmaf(a[r], b[c], acc[r][c]);
    }
  }
#pragma unroll
  for (int r = 0; r < 8; ++r) {
    int i = i0 + ty * 8 + r;
    float4 o0 = make_float4(acc[r][0] * alpha, acc[r][1] * alpha, acc[r][2] * alpha, acc[r][3] * alpha);
    float4 o1 = make_float4(acc[r][4] * alpha, acc[r][5] * alpha, acc[r][6] * alpha, acc[r][7] * alpha);
    *(float4*)&C[i * S + j0 + tx * 4] = o0;
    *(float4*)&C[i * S + j0 + 64 + tx * 4] = o1;
  }
}

// ---------------------------------------------------------------------------
// out[j*S+i] = in[i*S+j]  (64x64 LDS tiles)
// ---------------------------------------------------------------------------
__global__ __launch_bounds__(256) void transpose_k(const float* __restrict__ in,
                                                   float* __restrict__ out) {
  __shared__ float tile[64][65];
  int i0 = blockIdx.y * 64, j0 = blockIdx.x * 64;
  int tx = threadIdx.x & 63, ty = threadIdx.x >> 6;  // ty 0..3
#pragma unroll
  for (int r = 0; r < 16; ++r) {
    int row = r * 4 + ty;
    tile[row][tx] = in[(i0 + row) * S + j0 + tx];
  }
  __syncthreads();
#pragma unroll
  for (int r = 0; r < 16; ++r) {
    int row = r * 4 + ty;
    out[(j0 + row) * S + i0 + tx] = tile[tx][row];
  }
}

// ---------------------------------------------------------------------------
// Fast grid barrier v2: DISTRIBUTED arrival flags (one cache line per block,
// plain release store -> zero RMW serialization; round-4's single fetch_add
// counter measured ~15.9 us/barrier = 256 x ~60 ns serialized LLC RMWs).
// Block 0 wave 0 polls all 256 flags wave-parallel (4 loads/lane + __all),
// then release-stores a go flag the other blocks spin on.
// Requires co-residency -> hipLaunchCooperativeKernel.
// ---------------------------------------------------------------------------
__device__ __forceinline__ void grid_barrier(unsigned* __restrict__ arrive,
                                             unsigned* __restrict__ go,
                                             unsigned barnum) {
  __syncthreads();
  int t = threadIdx.x;
  if (blockIdx.x == 0) {
    if (t < 64) {
      if (t == 0)
        __hip_atomic_store(&arrive[0], barnum, __ATOMIC_RELEASE, __HIP_MEMORY_SCOPE_AGENT);
      for (;;) {
        bool mine = true;
#pragma unroll
        for (int k = 0; k < 4; ++k) {
          unsigned f = __hip_atomic_load(&arrive[(t + 64 * k) * FLAG_STRIDE],
                                         __ATOMIC_RELAXED, __HIP_MEMORY_SCOPE_AGENT);
          mine &= (f >= barnum);
        }
        if (__all(mine)) break;
        __builtin_amdgcn_s_sleep(1);
      }
      __threadfence();   // acquire: pull all blocks' released data
      if (t == 0)
        __hip_atomic_store(go, barnum, __ATOMIC_RELEASE, __HIP_MEMORY_SCOPE_AGENT);
    }
  } else {
    if (t == 0) {
      __hip_atomic_store(&arrive[(unsigned)blockIdx.x * FLAG_STRIDE], barnum,
                         __ATOMIC_RELEASE, __HIP_MEMORY_SCOPE_AGENT);
      while (__hip_atomic_load(go, __ATOMIC_RELAXED, __HIP_MEMORY_SCOPE_AGENT) < barnum)
        __builtin_amdgcn_s_sleep(2);
      __threadfence();   // acquire
    }
  }
  __syncthreads();
}

// ---------------------------------------------------------------------------
// PERSISTENT SINKHORN: one cooperative dispatch, all 500 iterations.
// Grid 256 blocks x 1024 threads (1 block/CU, co-resident). Each row owned by
// a wave pair (wave = 2*r_loc + h); each thread holds 16 cols of its Gp row
// and 16 cols of its GpT row in registers -> G is NEVER re-read during
// iteration (FETCH_SIZE ~54 MB/dispatch = initial load only, round-4 data).
// ---------------------------------------------------------------------------
__global__ __launch_bounds__(1024, 4) void sinkhorn_k(const float* __restrict__ Gp,
                                                      const float* __restrict__ GpT,
                                                      const float* __restrict__ lmu,
                                                      const float* __restrict__ lnu,
                                                      float* __restrict__ ut,
                                                      float* __restrict__ vt,
                                                      unsigned* __restrict__ arrive,
                                                      unsigned* __restrict__ go) {
  int t = threadIdx.x;
  int wave = t >> 6, lane = t & 63;
  int r_loc = wave >> 1;            // 0..7
  int h = wave & 1;                 // row half
  int row = blockIdx.x * 8 + r_loc;
  int cbase = h * 1024 + lane * 16;

  float a[16], b[16];
#pragma unroll
  for (int q = 0; q < 4; ++q) {
    *(float4*)&a[q * 4] = *(const float4*)&Gp[(size_t)row * S + cbase + q * 4];
    *(float4*)&b[q * 4] = *(const float4*)&GpT[(size_t)row * S + cbase + q * 4];
  }
  float lm = lmu[row];
  float ln = lnu[row];

  __shared__ float redmax[8][2];
  __shared__ float redsum[8][2];

  unsigned barnum = 0;
  for (int it = 0; it < ITERS; ++it) {
    // ---- phase A: ut[row] = lmu[row] - LSE_c(Gp[row][c] + vt[c]) ----
    {
      float p[16];
#pragma unroll
      for (int q = 0; q < 4; ++q) *(float4*)&p[q * 4] = *(const float4*)&vt[cbase + q * 4];
      float m = -3.4e38f;
#pragma unroll
      for (int k = 0; k < 16; ++k) { p[k] += a[k]; m = fmaxf(m, p[k]); }
#pragma unroll
      for (int off = 32; off; off >>= 1) m = fmaxf(m, __shfl_xor(m, off));
      if (lane == 0) redmax[r_loc][h] = m;
      __syncthreads();
      m = fmaxf(redmax[r_loc][0], redmax[r_loc][1]);
      float s = 0.f;
#pragma unroll
      for (int k = 0; k < 16; ++k) s += __expf(p[k] - m);
#pragma unroll
      for (int off = 32; off; off >>= 1) s += __shfl_xor(s, off);
      if (lane == 0) redsum[r_loc][h] = s;
      __syncthreads();
      if (h == 0 && lane == 0)
        ut[row] = lm - (m + __logf(redsum[r_loc][0] + redsum[r_loc][1]));
    }
    ++barnum;
    grid_barrier(arrive, go, barnum);
    // ---- phase B: vt[row] = lnu[row] - LSE_c(GpT[row][c] + ut[c]) ----
    {
      float p[16];
#pragma unroll
      for (int q = 0; q < 4; ++q) *(float4*)&p[q * 4] = *(const float4*)&ut[cbase + q * 4];
      float m = -3.4e38f;
#pragma unroll
      for (int k = 0; k < 16; ++k) { p[k] += b[k]; m = fmaxf(m, p[k]); }
#pragma unroll
      for (int off = 32; off; off >>= 1) m = fmaxf(m, __shfl_xor(m, off));
      if (lane == 0) redmax[r_loc][h] = m;
      __syncthreads();
      m = fmaxf(redmax[r_loc][0], redmax[r_loc][1]);
      float s = 0.f;
#pragma unroll
      for (int k = 0; k < 16; ++k) s += __expf(p[k] - m);
#pragma unroll
      for (int off = 32; off; off >>= 1) s += __shfl_xor(s, off);
      if (lane == 0) redsum[r_loc][h] = s;
      __syncthreads();
      if (h == 0 && lane == 0)
        vt[row] = ln - (m + __logf(redsum[r_loc][0] + redsum[r_loc][1]));
    }
    if (it + 1 < ITERS) {           // final visibility handled by dispatch boundary
      ++barnum;
      grid_barrier(arrive, go, barnum);
    }
  }
}

// ---------------------------------------------------------------------------
// RT[d,i] = sum_j TF[d,j] * exp( GpT[j*S+i] + ut[i] + vt[j] )
// (C = A * P^T with P^T generated on the fly into LDS; 128x128 tile, BK=16)
// ---------------------------------------------------------------------------
__global__ __launch_bounds__(256) void rt_gemm_k(const float* __restrict__ TF,
                                                 const float* __restrict__ GpT,
                                                 const float* __restrict__ ut,
                                                 const float* __restrict__ vt,
                                                 float* __restrict__ RT) {
  __shared__ float As[16][128];  // As[kk][dd] = TF[(d0+dd)*S + k0+kk]
  __shared__ float Bs[16][128];  // Bs[kk][ii] = P^T[k0+kk, i0+ii]
  int t = threadIdx.x;
  int d0 = blockIdx.y * 128, i0 = blockIdx.x * 128;
  int tx = t & 15, ty = t >> 4;
  float acc[8][8];
#pragma unroll
  for (int r = 0; r < 8; ++r)
#pragma unroll
    for (int c = 0; c < 8; ++c) acc[r][c] = 0.f;

  int akk = (t * 4) & 15, add0 = t >> 2;            // add0 in 0..63, + 64 for 2nd half
  int eb = t * 4;
  int bkk0 = eb >> 7, bii = eb & 127, bkk1 = bkk0 + 8;
  float4 u4 = *(const float4*)&ut[i0 + bii];        // loop-invariant

  for (int k0 = 0; k0 < S; k0 += 16) {
    float4 av0 = *(const float4*)&TF[(d0 + add0) * S + k0 + akk];
    float4 av1 = *(const float4*)&TF[(d0 + add0 + 64) * S + k0 + akk];
    float4 g0 = *(const float4*)&GpT[(k0 + bkk0) * S + i0 + bii];
    float4 g1 = *(const float4*)&GpT[(k0 + bkk1) * S + i0 + bii];
    float v0 = vt[k0 + bkk0], v1 = vt[k0 + bkk1];
    __syncthreads();
    As[akk + 0][add0] = av0.x; As[akk + 1][add0] = av0.y;
    As[akk + 2][add0] = av0.z; As[akk + 3][add0] = av0.w;
    As[akk + 0][add0 + 64] = av1.x; As[akk + 1][add0 + 64] = av1.y;
    As[akk + 2][add0 + 64] = av1.z; As[akk + 3][add0 + 64] = av1.w;
    float4 p0 = make_float4(__expf(g0.x + u4.x + v0), __expf(g0.y + u4.y + v0),
                            __expf(g0.z + u4.z + v0), __expf(g0.w + u4.w + v0));
    float4 p1 = make_float4(__expf(g1.x + u4.x + v1), __expf(g1.y + u4.y + v1),
                            __expf(g1.z + u4.z + v1), __expf(g1.w + u4.w + v1));
    *(float4*)&Bs[bkk0][bii] = p0;
    *(float4*)&Bs[bkk1][bii] = p1;
    __syncthreads();
#pragma unroll
    for (int kk = 0; kk < 16; ++kk) {
      float a[8], b[8];
      *(float4*)&a[0] = *(const float4*)&As[kk][ty * 8];
      *(float4*)&a[4] = *(const float4*)&As[kk][ty * 8 + 4];
      *(float4*)&b[0] = *(const float4*)&Bs[kk][tx * 4];
      *(float4*)&b[4] = *(const float4*)&Bs[kk][64 + tx * 4];
#pragma unroll
      for (int r = 0; r < 8; ++r)
#pragma unroll
        for (int c = 0; c < 8; ++c) acc[r][c] = fmaf(a[r], b[c], acc[r][c]);
    }
  }
#pragma unroll
  for (int r = 0; r < 8; ++r) {
    int d = d0 + ty * 8 + r;
    *(float4*)&RT[d * S + i0 + tx * 4] = *(float4*)&acc[r][0];
    *(float4*)&RT[d * S + i0 + 64 + tx * 4] = *(float4*)&acc[r][4];
  }
}

// dist2[i] += sum_{d in chunk} (qa[i]*QF[d,i] - RT[d,i])^2
__global__ __launch_bounds__(256) void dist2_partial_k(const float* __restrict__ QF,
                                                       const float* __restrict__ RT,
                                                       const float* __restrict__ qa,
                                                       float* __restrict__ dist2) {
  int ib = blockIdx.x & 7, dc = blockIdx.x >> 3;
  int i = ib * 256 + threadIdx.x;
  float qai = qa[i];
  float acc = 0.f;
  int d0 = dc * 256;
  for (int d = d0; d < d0 + 256; ++d) {
    float q = QF[d * S + i];
    float r = RT[d * S + i];
    float x = fmaf(qai, q, -r);
    acc = fmaf(x, x, acc);
  }
  atomicAdd(&dist2[i], acc);
}

__global__ __launch_bounds__(256) void loss_final_k(const float* __restrict__ dist2,
                                                    const float* __restrict__ label,
                                                    float* __restrict__ out) {
  int t = threadIdx.x;
  float acc = 0.f;
#pragma unroll
  for (int k = 0; k < 8; ++k) {
    int i = t + k * 256;
    float d2 = dist2[i];
    float dist = sqrtf(d2);
    float lab = label[i];
    float neg = fmaxf(MARGIN - dist, 0.f);
    acc += 0.5f * lab * d2 + 0.5f * (1.f - lab) * neg * neg;
  }
#pragma unroll
  for (int off = 32; off; off >>= 1) acc += __shfl_xor(acc, off);
  __shared__ float wsum[4];
  int wave = t >> 6, lane = t & 63;
  if (lane == 0) wsum[wave] = acc;
  __syncthreads();
  if (t == 0) out[0] = wsum[0] + wsum[1] + wsum[2] + wsum[3];
}

// ---------------------------------------------------------------------------
extern "C" void kernel_launch(void* const* d_in, const int* in_sizes, int n_in,
                              void* d_out, int out_size, void* d_ws, size_t ws_size,
                              hipStream_t stream) {
  const float* QF  = (const float*)d_in[0];  // [D, m] d-major
  const float* qa  = (const float*)d_in[1];  // [m]
  const float* TF  = (const float*)d_in[2];  // [D, n] d-major
  const float* ta  = (const float*)d_in[3];  // [n]
  const float* lab = (const float*)d_in[4];  // [m]
  float* out = (float*)d_out;

  float* ws = (float*)d_ws;
  float* Gp    = ws;                  // S*S : G' = -2 X^T Y  (reused as RT later)
  float* GpT   = Gp + S * S;          // S*S : G'^T
  float* ut    = GpT + S * S;         // S
  float* vt    = ut + S;              // S
  float* lmu   = vt + S;              // S
  float* lnu   = lmu + S;             // S
  float* dist2 = lnu + S;             // S
  unsigned* arrive = (unsigned*)(dist2 + S);       // NBLK*FLAG_STRIDE uints (128B-aligned)
  unsigned* go     = arrive + NBLK * FLAG_STRIDE;  // own cache line
  // total: 2*S*S + 5*S floats + 8K+32 uints ~= 33.6 MB

  init_marg_k<<<8, 256, 0, stream>>>(qa, ta, lmu, lnu, vt, dist2, arrive, go);
  colsumsq_k<<<64, 256, 0, stream>>>(TF, vt);  // vt = y2 (== v0 + y2)
  gemm_tn_k<<<dim3(16, 16), 256, 0, stream>>>(QF, TF, Gp, -2.0f);
  transpose_k<<<dim3(32, 32), 256, 0, stream>>>(Gp, GpT);

  {
    const float* Gp_c = Gp;
    const float* GpT_c = GpT;
    const float* lmu_c = lmu;
    const float* lnu_c = lnu;
    float* ut_p = ut;
    float* vt_p = vt;
    unsigned* arr_p = arrive;
    unsigned* go_p = go;
    void* kargs[] = {(void*)&Gp_c, (void*)&GpT_c, (void*)&lmu_c, (void*)&lnu_c,
                     (void*)&ut_p, (void*)&vt_p, (void*)&arr_p, (void*)&go_p};
    hipLaunchCooperativeKernel((void*)sinkhorn_k, dim3(NBLK), dim3(1024),
                               kargs, 0, stream);
  }

  // RT = P @ tf computed transposed: RT[d,i]; aliases Gp (G' dead after sinkhorn)
  rt_gemm_k<<<dim3(16, 16), 256, 0, stream>>>(TF, GpT, ut, vt, Gp);
  dist2_partial_k<<<64, 256, 0, stream>>>(QF, Gp, qa, dist2);
  loss_final_k<<<1, 256, 0, stream>>>(dist2, lab, out);
}